// Round 9
// baseline (476.920 us; speedup 1.0000x reference)
//
#include <hip/hip_runtime.h>
#include <hip/hip_fp16.h>

#define N_NODES 100000
#define N_EDGES 1600000
#define D_FEAT 32

#define SB_SHIFT 9
#define BIN_SZ 512                         // nodes per bin (src and dst)
#define NBIN 196                           // ceil(100000/512)
#define CAP_S 10240                        // per-bin entry capacity (mean 8192, sigma 90)
#define CAP_D 10240
#define S1_BLOCKS 256
#define EDGES_PER_S1 (N_EDGES / S1_BLOCKS) // 6250

typedef float __attribute__((ext_vector_type(4))) f32x4;

// ---- K0: weighted[n][f] = fp16(src_feats[n][f] * cj[n]) (6.4 MB table) ----
__global__ __launch_bounds__(256) void lgc_weight(
    const f32x4* __restrict__ feats4,   // [N_NODES * 8]
    const float* __restrict__ cj,       // [N_NODES]
    __half2*     __restrict__ w2)       // [N_NODES * 16]
{
    int tid = blockIdx.x * 256 + threadIdx.x;   // exactly 800000
    float c = cj[tid >> 3];
    f32x4 v = __builtin_nontemporal_load(&feats4[tid]);
    w2[tid * 2 + 0] = __floats2half2_rn(v.x * c, v.y * c);
    w2[tid * 2 + 1] = __floats2half2_rn(v.z * c, v.w * c);
}

__device__ __forceinline__ void spill_row(const __half* __restrict__ weighted,
                                          float* __restrict__ out, int s, int d)
{
    const __half* row = weighted + (size_t)s * D_FEAT;
    float* o = out + (size_t)d * D_FEAT;
    for (int f = 0; f < D_FEAT; ++f) atomicAdd(o + f, __half2float(row[f]));
}

// ---- K1: partition edges by src-bin. LDS histogram -> one global atomic per
// (block,bin) -> dense per-bin appends. Entry = srcLocal(9) | dst(17)<<9.
__global__ __launch_bounds__(256) void lgc_part1(
    const int*    __restrict__ src_idx,
    const int*    __restrict__ dst_idx,
    const __half* __restrict__ weighted,
    int*          __restrict__ scnt,    // [NBIN] pre-zeroed
    int*          __restrict__ slist,   // [NBIN * CAP_S]
    float*        __restrict__ out)     // spill target (pre-zeroed)
{
    __shared__ int hist[NBIN];
    __shared__ int gbase[NBIN];
    __shared__ int run[NBIN];
    const int b = blockIdx.x, tid = threadIdx.x;
    const int e0 = b * EDGES_PER_S1;

    for (int i = tid; i < NBIN; i += 256) hist[i] = 0;
    __syncthreads();
    for (int i = tid; i < EDGES_PER_S1; i += 256) {
        int s = src_idx[e0 + i];
        atomicAdd(&hist[s >> SB_SHIFT], 1);
    }
    __syncthreads();
    for (int i = tid; i < NBIN; i += 256) {
        gbase[i] = atomicAdd(&scnt[i], hist[i]);
        run[i] = 0;
    }
    __syncthreads();
    for (int i = tid; i < EDGES_PER_S1; i += 256) {
        int s = src_idx[e0 + i];
        int d = dst_idx[e0 + i];
        int bin = s >> SB_SHIFT;
        int r = atomicAdd(&run[bin], 1);
        int pos = gbase[bin] + r;
        if (pos < CAP_S)
            slist[bin * CAP_S + pos] = (s & (BIN_SZ - 1)) | (d << SB_SHIFT);
        else
            spill_row(weighted, out, s, d);   // statistically never
    }
}

// ---- K2: per src-bin, re-partition by dst-bin. Output entries grouped by
// dst-bin in same-src-bin runs (K3 read locality). Entry = src(17) | dl(9)<<17.
__global__ __launch_bounds__(256) void lgc_part2(
    const int*    __restrict__ scnt,
    const int*    __restrict__ slist,
    const __half* __restrict__ weighted,
    int*          __restrict__ dcnt,    // [NBIN] pre-zeroed
    int*          __restrict__ dlist,   // [NBIN * CAP_D]
    float*        __restrict__ out)
{
    __shared__ int hist[NBIN];
    __shared__ int gbase[NBIN];
    __shared__ int run[NBIN];
    const int sb = blockIdx.x, tid = threadIdx.x;
    const int n = min(scnt[sb], CAP_S);
    const int* list = slist + sb * CAP_S;

    for (int i = tid; i < NBIN; i += 256) hist[i] = 0;
    __syncthreads();
    for (int i = tid; i < n; i += 256) {
        int d = list[i] >> SB_SHIFT;
        atomicAdd(&hist[d >> SB_SHIFT], 1);
    }
    __syncthreads();
    for (int i = tid; i < NBIN; i += 256) {
        gbase[i] = atomicAdd(&dcnt[i], hist[i]);
        run[i] = 0;
    }
    __syncthreads();
    const int sbase = sb << SB_SHIFT;
    for (int i = tid; i < n; i += 256) {
        int ent = list[i];
        int src = sbase + (ent & (BIN_SZ - 1));
        int d   = ent >> SB_SHIFT;
        int dbin = d >> SB_SHIFT, dl = d & (BIN_SZ - 1);
        int r = atomicAdd(&run[dbin], 1);
        int pos = gbase[dbin] + r;
        if (pos < CAP_D)
            dlist[dbin * CAP_D + pos] = src | (dl << 17);
        else
            spill_row(weighted, out, src, d);  // statistically never
    }
}

// ---- K3: block per dst-bin; 64KB LDS f32 accumulator. Lane = feat (2B fp16
// load; 32 lanes consume one full 64B row), conflict-free LDS atomicAdd.
// Reads hit L2-resident 32KB src-slices (same-src-bin runs from K2).
__global__ __launch_bounds__(1024) void lgc_accum(
    const __half* __restrict__ weighted,
    const float*  __restrict__ ci,
    const int*    __restrict__ dcnt,
    const int*    __restrict__ dlist,
    float*        __restrict__ out)
{
    __shared__ float acc[BIN_SZ * D_FEAT];   // 64 KB
    const int db = blockIdx.x, tid = threadIdx.x;
    for (int i = tid; i < BIN_SZ * D_FEAT; i += 1024) acc[i] = 0.f;
    __syncthreads();

    const int n = min(dcnt[db], CAP_D);
    const int* list = dlist + db * CAP_D;
    const int g = tid >> 5;       // 32 lane-groups per block
    const int l = tid & 31;       // feat index

    int i = g;
    for (; i + 96 < n; i += 128) {                 // unroll-4 for MLP
        int e0 = list[i], e1 = list[i + 32], e2 = list[i + 64], e3 = list[i + 96];
        float v0 = __half2float(weighted[(size_t)(e0 & 0x1FFFF) * D_FEAT + l]);
        float v1 = __half2float(weighted[(size_t)(e1 & 0x1FFFF) * D_FEAT + l]);
        float v2 = __half2float(weighted[(size_t)(e2 & 0x1FFFF) * D_FEAT + l]);
        float v3 = __half2float(weighted[(size_t)(e3 & 0x1FFFF) * D_FEAT + l]);
        atomicAdd(&acc[((e0 >> 17) & 511) * D_FEAT + l], v0);
        atomicAdd(&acc[((e1 >> 17) & 511) * D_FEAT + l], v1);
        atomicAdd(&acc[((e2 >> 17) & 511) * D_FEAT + l], v2);
        atomicAdd(&acc[((e3 >> 17) & 511) * D_FEAT + l], v3);
    }
    for (; i < n; i += 32) {
        int e = list[i];
        float v = __half2float(weighted[(size_t)(e & 0x1FFFF) * D_FEAT + l]);
        atomicAdd(&acc[((e >> 17) & 511) * D_FEAT + l], v);
    }
    __syncthreads();

    // flush: out = (acc + spill) * ci, float4-vectorized
    const int node0 = db << SB_SHIFT;
    float4* out4 = (float4*)(out + (size_t)node0 * D_FEAT);
    const float4* a4 = (const float4*)acc;
    for (int j = tid; j < BIN_SZ * (D_FEAT / 4); j += 1024) {
        int node = node0 + (j >> 3);
        if (node >= N_NODES) break;      // j monotonic per thread -> ok
        float c = ci[node];
        float4 a = a4[j];
        float4 o = out4[j];
        float4 r;
        r.x = (a.x + o.x) * c; r.y = (a.y + o.y) * c;
        r.z = (a.z + o.z) * c; r.w = (a.w + o.w) * c;
        out4[j] = r;
    }
}

// ---------------- round-1 fallback path (only if ws too small) ----------------
__global__ __launch_bounds__(256) void lgc_scatter(
    const float4* __restrict__ src_feats4,
    const float*  __restrict__ cj,
    const int*    __restrict__ src_idx,
    const int*    __restrict__ dst_idx,
    float*        __restrict__ out)
{
    long tid = (long)blockIdx.x * blockDim.x + threadIdx.x;
    const long total = (long)N_EDGES * 8;
    if (tid >= total) return;
    int e  = (int)(tid >> 3);
    int f4 = (int)(tid & 7);
    int s = src_idx[e];
    int d = dst_idx[e];
    float c = cj[s];
    float4 v = src_feats4[s * 8 + f4];
    float* o = out + (size_t)d * D_FEAT + f4 * 4;
    atomicAdd(o + 0, v.x * c);
    atomicAdd(o + 1, v.y * c);
    atomicAdd(o + 2, v.z * c);
    atomicAdd(o + 3, v.w * c);
}

__global__ __launch_bounds__(256) void lgc_scale(
    float4*       __restrict__ out4,
    const float*  __restrict__ ci)
{
    int tid = blockIdx.x * blockDim.x + threadIdx.x;
    const int total = N_NODES * 8;
    if (tid >= total) return;
    float c = ci[tid >> 3];
    float4 v = out4[tid];
    v.x *= c; v.y *= c; v.z *= c; v.w *= c;
    out4[tid] = v;
}

extern "C" void kernel_launch(void* const* d_in, const int* in_sizes, int n_in,
                              void* d_out, int out_size, void* d_ws, size_t ws_size,
                              hipStream_t stream) {
    const float* src_feats = (const float*)d_in[0];   // [100000, 32] f32
    const float* cj        = (const float*)d_in[1];   // [100000, 1]
    const float* ci        = (const float*)d_in[2];   // [100000, 1]
    const int*   src_idx   = (const int*)d_in[3];     // [1600000]
    const int*   dst_idx   = (const int*)d_in[4];     // [1600000]
    float*       out       = (float*)d_out;           // [100000, 32] f32

    // ws layout (ints): scnt[256] | dcnt[256] | slist[NBIN*CAP_S] |
    //                   dlist[NBIN*CAP_D] | weighted fp16 [N_NODES*32]
    const size_t off_scnt  = 0;
    const size_t off_dcnt  = 256;
    const size_t off_slist = 512;
    const size_t off_dlist = off_slist + (size_t)NBIN * CAP_S;
    const size_t off_w     = off_dlist + (size_t)NBIN * CAP_D;       // int offset
    const size_t need = off_w * 4 + (size_t)N_NODES * D_FEAT * sizeof(__half);

    if (ws_size >= need) {
        int*    scnt     = (int*)d_ws + off_scnt;
        int*    dcnt     = (int*)d_ws + off_dcnt;
        int*    slist    = (int*)d_ws + off_slist;
        int*    dlist    = (int*)d_ws + off_dlist;
        __half* weighted = (__half*)((int*)d_ws + off_w);

        hipMemsetAsync((int*)d_ws, 0, 512 * sizeof(int), stream);           // scnt+dcnt
        hipMemsetAsync(out, 0, (size_t)out_size * sizeof(float), stream);   // spill base

        lgc_weight<<<(N_NODES * 8) / 256, 256, 0, stream>>>(
            (const f32x4*)src_feats, cj, (__half2*)weighted);

        lgc_part1<<<S1_BLOCKS, 256, 0, stream>>>(
            src_idx, dst_idx, weighted, scnt, slist, out);

        lgc_part2<<<NBIN, 256, 0, stream>>>(
            scnt, slist, weighted, dcnt, dlist, out);

        lgc_accum<<<NBIN, 1024, 0, stream>>>(
            weighted, ci, dcnt, dlist, out);
    } else {
        hipMemsetAsync(out, 0, (size_t)out_size * sizeof(float), stream);
        {
            const long total = (long)N_EDGES * 8;
            const int grid = (int)((total + 255) / 256);
            lgc_scatter<<<grid, 256, 0, stream>>>((const float4*)src_feats, cj,
                                                  src_idx, dst_idx, out);
        }
        {
            const int grid = (N_NODES * 8 + 255) / 256;
            lgc_scale<<<grid, 256, 0, stream>>>((float4*)out, ci);
        }
    }
}

// Round 11
// 194.553 us; speedup vs baseline: 2.4514x; 2.4514x over previous
//
#include <hip/hip_runtime.h>
#include <hip/hip_fp16.h>

#define N_NODES 100000
#define N_EDGES 1600000
#define D_FEAT 32
#define CAP 32                        // Poisson(16): P(deg>32) tiny -> spill path
#define NXCD 8
#define NODES_PER_XCD (N_NODES / NXCD)            // 12500
#define EDGE_THREADS (N_EDGES / 4)                // 400000 (4 edges/thread)
#define EDGE_BLOCKS ((EDGE_THREADS + 255) / 256)  // 1563

typedef int   __attribute__((ext_vector_type(4))) i32x4;
typedef float __attribute__((ext_vector_type(4))) f32x4;
typedef unsigned __attribute__((ext_vector_type(2))) u32x2;

// ---- K0: split fp16 weighted tables. wlo = feats 0..15, whi = feats 16..31.
// Each table is 3.2 MB -> fits a 4 MB per-XCD L2 during its gather pass.
__global__ __launch_bounds__(256) void lgc_weight(
    const f32x4* __restrict__ feats4,   // [N_NODES * 8]
    const float* __restrict__ cj,       // [N_NODES]
    u32x2*       __restrict__ wlo,      // [N_NODES * 4] 8B units (4 fp16 feats)
    u32x2*       __restrict__ whi)      // [N_NODES * 4]
{
    int tid = blockIdx.x * 256 + threadIdx.x;   // exactly 800000
    int n = tid >> 3, f4 = tid & 7;
    float c = cj[n];
    f32x4 v = __builtin_nontemporal_load(&feats4[tid]);
    __half2 h0 = __floats2half2_rn(v.x * c, v.y * c);
    __half2 h1 = __floats2half2_rn(v.z * c, v.w * c);
    u32x2 u;
    u.x = *(const unsigned*)&h0;
    u.y = *(const unsigned*)&h1;
    u32x2* base = (f4 < 4) ? wlo : whi;
    base[(size_t)n * 4 + (f4 & 3)] = u;
}

__device__ __forceinline__ void spill_row(const __half* __restrict__ wlo,
                                          const __half* __restrict__ whi,
                                          float* __restrict__ out, int s, int d)
{
    float* o = out + (size_t)d * D_FEAT;
    for (int f = 0; f < 16; ++f)
        atomicAdd(o + f,      __half2float(wlo[(size_t)s * 16 + f]));
    for (int f = 0; f < 16; ++f)
        atomicAdd(o + 16 + f, __half2float(whi[(size_t)s * 16 + f]));
}

// ---- K1: bucket build (unchanged from R8): XCD x owns dst range; NT idx loads ----
__global__ __launch_bounds__(256) void lgc_bucket(
    const i32x4*  __restrict__ dst4,      // [N_EDGES/4]
    const i32x4*  __restrict__ src4,      // [N_EDGES/4]
    const __half* __restrict__ wlo,       // spill path only
    const __half* __restrict__ whi,
    int*          __restrict__ cnt,       // [N_NODES], pre-zeroed
    int*          __restrict__ bucket,    // [N_NODES * CAP]
    float*        __restrict__ out)       // pre-zeroed; overflow spill target
{
    int x  = blockIdx.x % NXCD;
    int lb = blockIdx.x / NXCD;
    int t  = lb * 256 + threadIdx.x;
    if (t >= EDGE_THREADS) return;

    const int lo = x * NODES_PER_XCD;
    const int hi = lo + NODES_PER_XCD;

    i32x4 d4 = __builtin_nontemporal_load(&dst4[t]);
    bool ix = (d4.x >= lo) & (d4.x < hi);
    bool iy = (d4.y >= lo) & (d4.y < hi);
    bool iz = (d4.z >= lo) & (d4.z < hi);
    bool iw = (d4.w >= lo) & (d4.w < hi);
    if (!(ix | iy | iz | iw)) return;

    i32x4 s4 = __builtin_nontemporal_load(&src4[t]);
    int ds[4] = {d4.x, d4.y, d4.z, d4.w};
    int ss[4] = {s4.x, s4.y, s4.z, s4.w};
    bool in[4] = {ix, iy, iz, iw};

    #pragma unroll
    for (int k = 0; k < 4; ++k) {
        if (!in[k]) continue;
        int d = ds[k], s = ss[k];
        int pos = atomicAdd(&cnt[d], 1);
        if (pos < CAP) {
            bucket[(size_t)d * CAP + pos] = s;
        } else {
            spill_row(wlo, whi, out, s, d);   // statistically never
        }
    }
}

// ---- K2a/K2b: gather over ONE feature-half. Table w is 3.2 MB (L2-resident).
// 4 lanes per node, each lane reads 8B (4 fp16 feats) per edge.
__global__ __launch_bounds__(256) void lgc_gather_half(
    const u32x2* __restrict__ w,         // [N_NODES * 4] (one half-table)
    const float* __restrict__ ci,
    const int*   __restrict__ cnt,
    const i32x4* __restrict__ bucket4,   // [N_NODES * CAP/4]
    f32x4*       __restrict__ outh)      // (f32x4*)out + part*4; row stride 8
{
    int tid = blockIdx.x * 256 + threadIdx.x;
    if (tid >= N_NODES * 4) return;
    int n = tid >> 2;
    int q = tid & 3;                     // 4-feat slice within the half

    int c = cnt[n];
    if (c > CAP) c = CAP;
    const i32x4* b4 = bucket4 + (size_t)n * (CAP / 4);

    i32x4 r[8];
    #pragma unroll
    for (int j = 0; j < 8; ++j)
        if (j * 4 < c) r[j] = __builtin_nontemporal_load(&b4[j]);

    float a0 = 0.f, a1 = 0.f, a2 = 0.f, a3 = 0.f;
    auto row = [&](int s) {
        u32x2 u = w[(size_t)s * 4 + q];
        unsigned ux = u.x, uy = u.y;
        __half2 p0 = *(__half2*)&ux;
        __half2 p1 = *(__half2*)&uy;
        float2 f0 = __half22float2(p0);
        float2 f1 = __half22float2(p1);
        a0 += f0.x; a1 += f0.y; a2 += f1.x; a3 += f1.y;
    };

    #pragma unroll
    for (int j = 0; j < 8; ++j) {
        int base = j * 4;
        if (base < c) {
            i32x4 bv = r[j];
            row(bv.x);
            if (base + 1 < c) row(bv.y);
            if (base + 2 < c) row(bv.z);
            if (base + 3 < c) row(bv.w);
        }
    }

    float sc = ci[n];
    f32x4* op = outh + (size_t)n * 8 + q;
    f32x4 o = __builtin_nontemporal_load(op);        // spill base (normally 0)
    f32x4 res;
    res.x = (a0 + o.x) * sc;
    res.y = (a1 + o.y) * sc;
    res.z = (a2 + o.z) * sc;
    res.w = (a3 + o.w) * sc;
    __builtin_nontemporal_store(res, op);
}

// ---------------- round-1 fallback path (only if ws too small) ----------------
__global__ __launch_bounds__(256) void lgc_scatter(
    const float4* __restrict__ src_feats4,
    const float*  __restrict__ cj,
    const int*    __restrict__ src_idx,
    const int*    __restrict__ dst_idx,
    float*        __restrict__ out)
{
    long tid = (long)blockIdx.x * blockDim.x + threadIdx.x;
    const long total = (long)N_EDGES * 8;
    if (tid >= total) return;
    int e  = (int)(tid >> 3);
    int f4 = (int)(tid & 7);
    int s = src_idx[e];
    int d = dst_idx[e];
    float c = cj[s];
    float4 v = src_feats4[s * 8 + f4];
    float* o = out + (size_t)d * D_FEAT + f4 * 4;
    atomicAdd(o + 0, v.x * c);
    atomicAdd(o + 1, v.y * c);
    atomicAdd(o + 2, v.z * c);
    atomicAdd(o + 3, v.w * c);
}

__global__ __launch_bounds__(256) void lgc_scale(
    float4*       __restrict__ out4,
    const float*  __restrict__ ci)
{
    int tid = blockIdx.x * blockDim.x + threadIdx.x;
    const int total = N_NODES * 8;
    if (tid >= total) return;
    float c = ci[tid >> 3];
    float4 v = out4[tid];
    v.x *= c; v.y *= c; v.z *= c; v.w *= c;
    out4[tid] = v;
}

extern "C" void kernel_launch(void* const* d_in, const int* in_sizes, int n_in,
                              void* d_out, int out_size, void* d_ws, size_t ws_size,
                              hipStream_t stream) {
    const float* src_feats = (const float*)d_in[0];   // [100000, 32] f32
    const float* cj        = (const float*)d_in[1];   // [100000, 1]
    const float* ci        = (const float*)d_in[2];   // [100000, 1]
    const int*   src_idx   = (const int*)d_in[3];     // [1600000]
    const int*   dst_idx   = (const int*)d_in[4];     // [1600000]
    float*       out       = (float*)d_out;           // [100000, 32] f32

    // ws (ints): cnt[102400] | bucket[N_NODES*CAP] | wlo[3.2MB] | whi[3.2MB]
    const size_t cnt_ints    = 102400;                    // 0.4 MB
    const size_t bucket_ints = (size_t)N_NODES * CAP;     // 12.8 MB
    const size_t wtab_bytes  = (size_t)N_NODES * 16 * sizeof(__half); // 3.2 MB each
    const size_t need = (cnt_ints + bucket_ints) * 4 + 2 * wtab_bytes;

    if (ws_size >= need) {
        int*    cnt    = (int*)d_ws;
        int*    bucket = cnt + cnt_ints;
        __half* wlo    = (__half*)(bucket + bucket_ints);
        __half* whi    = wlo + (size_t)N_NODES * 16;

        hipMemsetAsync(cnt, 0, N_NODES * sizeof(int), stream);
        hipMemsetAsync(out, 0, (size_t)out_size * sizeof(float), stream);

        lgc_weight<<<(N_NODES * 8) / 256, 256, 0, stream>>>(
            (const f32x4*)src_feats, cj, (u32x2*)wlo, (u32x2*)whi);

        lgc_bucket<<<NXCD * EDGE_BLOCKS, 256, 0, stream>>>(
            (const i32x4*)dst_idx, (const i32x4*)src_idx, wlo, whi,
            cnt, bucket, out);

        const int ggrid = (N_NODES * 4 + 255) / 256;
        lgc_gather_half<<<ggrid, 256, 0, stream>>>(
            (const u32x2*)wlo, ci, cnt, (const i32x4*)bucket,
            (f32x4*)out + 0);
        lgc_gather_half<<<ggrid, 256, 0, stream>>>(
            (const u32x2*)whi, ci, cnt, (const i32x4*)bucket,
            (f32x4*)out + 4);
    } else {
        hipMemsetAsync(out, 0, (size_t)out_size * sizeof(float), stream);
        {
            const long total = (long)N_EDGES * 8;
            const int grid = (int)((total + 255) / 256);
            lgc_scatter<<<grid, 256, 0, stream>>>((const float4*)src_feats, cj,
                                                  src_idx, dst_idx, out);
        }
        {
            const int grid = (N_NODES * 8 + 255) / 256;
            lgc_scale<<<grid, 256, 0, stream>>>((float4*)out, ci);
        }
    }
}

// Round 12
// 180.318 us; speedup vs baseline: 2.6449x; 1.0789x over previous
//
#include <hip/hip_runtime.h>
#include <hip/hip_fp16.h>

#define N_NODES 100000
#define N_EDGES 1600000
#define D_FEAT 32
#define CAP 32                        // Poisson(16): P(deg>32) tiny -> spill path
#define NPASS 4                       // dst-range passes (was 8)
#define NODES_PER_P (N_NODES / NPASS)             // 25000
#define EDGE_THREADS (N_EDGES / 4)                // 400000 (4 edges/thread)
#define EDGE_BLOCKS ((EDGE_THREADS + 255) / 256)  // 1563

typedef int   __attribute__((ext_vector_type(4))) i32x4;
typedef float __attribute__((ext_vector_type(4))) f32x4;

// ---- K0: weighted[n][f] = fp16(src_feats[n][f] * cj[n]) (6.4 MB table) ----
__global__ __launch_bounds__(256) void lgc_weight(
    const f32x4* __restrict__ feats4,   // [N_NODES * 8]
    const float* __restrict__ cj,       // [N_NODES]
    __half2*     __restrict__ w2)       // [N_NODES * 16]
{
    int tid = blockIdx.x * 256 + threadIdx.x;   // exactly 800000
    float c = cj[tid >> 3];
    f32x4 v = __builtin_nontemporal_load(&feats4[tid]);
    w2[tid * 2 + 0] = __floats2half2_rn(v.x * c, v.y * c);
    w2[tid * 2 + 1] = __floats2half2_rn(v.z * c, v.w * c);
}

__device__ __forceinline__ void spill_row(const __half* __restrict__ weighted,
                                          float* __restrict__ out, int s, int d)
{
    const __half* row = weighted + (size_t)s * D_FEAT;
    float* o = out + (size_t)d * D_FEAT;
    for (int f = 0; f < D_FEAT; ++f) atomicAdd(o + f, __half2float(row[f]));
}

// ---- K1: bucket build, 4 dst-range passes (pass p on XCDs {p, p+4}); NT idx loads ----
__global__ __launch_bounds__(256) void lgc_bucket(
    const i32x4*  __restrict__ dst4,      // [N_EDGES/4]
    const i32x4*  __restrict__ src4,      // [N_EDGES/4]
    const __half* __restrict__ weighted,  // spill path only
    int*          __restrict__ cnt,       // [N_NODES], pre-zeroed
    int*          __restrict__ bucket,    // [N_NODES * CAP]
    float*        __restrict__ out)       // pre-zeroed; overflow spill target
{
    int x  = blockIdx.x % NPASS;          // dst-range this block handles
    int lb = blockIdx.x / NPASS;
    int t  = lb * 256 + threadIdx.x;
    if (t >= EDGE_THREADS) return;

    const int lo = x * NODES_PER_P;
    const int hi = lo + NODES_PER_P;

    i32x4 d4 = __builtin_nontemporal_load(&dst4[t]);
    bool ix = (d4.x >= lo) & (d4.x < hi);
    bool iy = (d4.y >= lo) & (d4.y < hi);
    bool iz = (d4.z >= lo) & (d4.z < hi);
    bool iw = (d4.w >= lo) & (d4.w < hi);
    if (!(ix | iy | iz | iw)) return;

    i32x4 s4 = __builtin_nontemporal_load(&src4[t]);
    int ds[4] = {d4.x, d4.y, d4.z, d4.w};
    int ss[4] = {s4.x, s4.y, s4.z, s4.w};
    bool in[4] = {ix, iy, iz, iw};

    #pragma unroll
    for (int k = 0; k < 4; ++k) {
        if (!in[k]) continue;
        int d = ds[k], s = ss[k];
        int pos = atomicAdd(&cnt[d], 1);
        if (pos < CAP) {
            bucket[(size_t)d * CAP + pos] = s;
        } else {
            spill_row(weighted, out, s, d);   // statistically never
        }
    }
}

// ---- K2: gather-sum, 4 lanes/node, 16B fp16 row-slice per edge. Explicit
// 8-deep load batching: 8 independent uint4 loads issued before ANY use,
// guaranteeing >=8 outstanding misses per thread on the random-read chain.
__global__ __launch_bounds__(256) void lgc_gather(
    const uint4* __restrict__ w4,        // [N_NODES * 4] 16B units (8 fp16 feats)
    const float* __restrict__ ci,
    const int*   __restrict__ cnt,
    const i32x4* __restrict__ bucket4,   // [N_NODES * CAP/4]
    f32x4*       __restrict__ out4)      // [N_NODES * 8]
{
    int tid = blockIdx.x * 256 + threadIdx.x;
    if (tid >= N_NODES * 4) return;
    int n = tid >> 2;
    int q = tid & 3;                     // 8-feat slice

    int c = cnt[n];
    if (c > CAP) c = CAP;
    const i32x4* b4 = bucket4 + (size_t)n * (CAP / 4);

    i32x4 r[8];
    #pragma unroll
    for (int j = 0; j < 8; ++j)
        if (j * 4 < c) r[j] = __builtin_nontemporal_load(&b4[j]);

    float acc[8] = {0.f, 0.f, 0.f, 0.f, 0.f, 0.f, 0.f, 0.f};

    #pragma unroll
    for (int b = 0; b < 4; ++b) {
        const int base = b * 8;
        if (base < c) {
            int m = c - base;                  // 1..8 valid edges this batch
            uint4 v[8];
            #pragma unroll
            for (int t = 0; t < 8; ++t) {      // phase 1: issue 8 loads
                if (t < m) {
                    int s = ((const int*)r)[base + t];   // compile-time reg index
                    v[t] = w4[(size_t)s * 4 + q];
                }
            }
            #pragma unroll
            for (int t = 0; t < 8; ++t) {      // phase 2: convert + accumulate
                if (t < m) {
                    unsigned ux = v[t].x, uy = v[t].y, uz = v[t].z, uw = v[t].w;
                    float2 f0 = __half22float2(*(__half2*)&ux);
                    float2 f1 = __half22float2(*(__half2*)&uy);
                    float2 f2 = __half22float2(*(__half2*)&uz);
                    float2 f3 = __half22float2(*(__half2*)&uw);
                    acc[0] += f0.x; acc[1] += f0.y; acc[2] += f1.x; acc[3] += f1.y;
                    acc[4] += f2.x; acc[5] += f2.y; acc[6] += f3.x; acc[7] += f3.y;
                }
            }
        }
    }

    float sc = ci[n];
    size_t ob = (size_t)n * 8 + q * 2;
    f32x4 o0 = __builtin_nontemporal_load(&out4[ob]);      // spill base (normally 0)
    f32x4 o1 = __builtin_nontemporal_load(&out4[ob + 1]);
    f32x4 a0 = {acc[0], acc[1], acc[2], acc[3]};
    f32x4 a1 = {acc[4], acc[5], acc[6], acc[7]};
    __builtin_nontemporal_store((a0 + o0) * sc, &out4[ob]);
    __builtin_nontemporal_store((a1 + o1) * sc, &out4[ob + 1]);
}

// ---------------- round-1 fallback path (only if ws too small) ----------------
__global__ __launch_bounds__(256) void lgc_scatter(
    const float4* __restrict__ src_feats4,
    const float*  __restrict__ cj,
    const int*    __restrict__ src_idx,
    const int*    __restrict__ dst_idx,
    float*        __restrict__ out)
{
    long tid = (long)blockIdx.x * blockDim.x + threadIdx.x;
    const long total = (long)N_EDGES * 8;
    if (tid >= total) return;
    int e  = (int)(tid >> 3);
    int f4 = (int)(tid & 7);
    int s = src_idx[e];
    int d = dst_idx[e];
    float c = cj[s];
    float4 v = src_feats4[s * 8 + f4];
    float* o = out + (size_t)d * D_FEAT + f4 * 4;
    atomicAdd(o + 0, v.x * c);
    atomicAdd(o + 1, v.y * c);
    atomicAdd(o + 2, v.z * c);
    atomicAdd(o + 3, v.w * c);
}

__global__ __launch_bounds__(256) void lgc_scale(
    float4*       __restrict__ out4,
    const float*  __restrict__ ci)
{
    int tid = blockIdx.x * blockDim.x + threadIdx.x;
    const int total = N_NODES * 8;
    if (tid >= total) return;
    float c = ci[tid >> 3];
    float4 v = out4[tid];
    v.x *= c; v.y *= c; v.z *= c; v.w *= c;
    out4[tid] = v;
}

extern "C" void kernel_launch(void* const* d_in, const int* in_sizes, int n_in,
                              void* d_out, int out_size, void* d_ws, size_t ws_size,
                              hipStream_t stream) {
    const float* src_feats = (const float*)d_in[0];   // [100000, 32] f32
    const float* cj        = (const float*)d_in[1];   // [100000, 1]
    const float* ci        = (const float*)d_in[2];   // [100000, 1]
    const int*   src_idx   = (const int*)d_in[3];     // [1600000]
    const int*   dst_idx   = (const int*)d_in[4];     // [1600000]
    float*       out       = (float*)d_out;           // [100000, 32] f32

    // ws layout: cnt[102400 ints] | bucket[N_NODES*CAP ints] | weighted[N_NODES*32 fp16]
    const size_t cnt_ints    = 102400;                    // 0.4 MB
    const size_t bucket_ints = (size_t)N_NODES * CAP;     // 12.8 MB
    const size_t wfeat_bytes = (size_t)N_NODES * D_FEAT * sizeof(__half); // 6.4 MB
    const size_t need = (cnt_ints + bucket_ints) * 4 + wfeat_bytes;

    if (ws_size >= need) {
        int*    cnt      = (int*)d_ws;
        int*    bucket   = cnt + cnt_ints;
        __half* weighted = (__half*)(bucket + bucket_ints);

        hipMemsetAsync(cnt, 0, N_NODES * sizeof(int), stream);
        hipMemsetAsync(out, 0, (size_t)out_size * sizeof(float), stream);

        lgc_weight<<<(N_NODES * 8) / 256, 256, 0, stream>>>(
            (const f32x4*)src_feats, cj, (__half2*)weighted);

        lgc_bucket<<<NPASS * EDGE_BLOCKS, 256, 0, stream>>>(
            (const i32x4*)dst_idx, (const i32x4*)src_idx, weighted,
            cnt, bucket, out);

        lgc_gather<<<(N_NODES * 4 + 255) / 256, 256, 0, stream>>>(
            (const uint4*)weighted, ci, cnt, (const i32x4*)bucket, (f32x4*)out);
    } else {
        hipMemsetAsync(out, 0, (size_t)out_size * sizeof(float), stream);
        {
            const long total = (long)N_EDGES * 8;
            const int grid = (int)((total + 255) / 256);
            lgc_scatter<<<grid, 256, 0, stream>>>((const float4*)src_feats, cj,
                                                  src_idx, dst_idx, out);
        }
        {
            const int grid = (N_NODES * 8 + 255) / 256;
            lgc_scale<<<grid, 256, 0, stream>>>((float4*)out, ci);
        }
    }
}